// Round 8
// baseline (168.253 us; speedup 1.0000x reference)
//
#include <hip/hip_runtime.h>
#include <math.h>

#define NVOX 50000
#define PPTS 32
#define HDIM 64
#define ODIM 128
#define EPSBN 1e-5f

typedef _Float16 f16x8 __attribute__((ext_vector_type(8)));
typedef _Float16 f16x4 __attribute__((ext_vector_type(4)));
typedef float f32x4 __attribute__((ext_vector_type(4)));

#define LO4(v) __builtin_shufflevector(v, v, 0, 1, 2, 3)
#define HI4(v) __builtin_shufflevector(v, v, 4, 5, 6, 7)

// d_ws layout (f16 elements unless noted):
//   [0, 512)       W1c: 64 rows x 8 f16  {w0..w3, c1, 0,0,0}  (BN-folded layer1)
//   [512, 4608)    W2F frag-major: [ch'][q][kc][j] = W2f[16kc+4q+j][ch']
//   [4608, 12800)  W3F frag-major + granule-swizzled:
//                  row o, physical granule php holds logical granule
//                  gl = php ^ (o&7); logical row = [q][kc][j] -> W3[16kc+4q+j][o]
//   byte 25600:    f32 c2[64], f32 b3[128]
#define WS_W1C 0
#define WS_W2T 512
#define WS_W3T 4608
#define WS_F32_BYTE 25600
#define FOLD_THREADS 12992

__global__ void vfe_fold(
    const float* __restrict__ W1, const float* __restrict__ b1,
    const float* __restrict__ g1, const float* __restrict__ be1,
    const float* __restrict__ m1, const float* __restrict__ v1,
    const float* __restrict__ W2, const float* __restrict__ b2,
    const float* __restrict__ g2, const float* __restrict__ be2,
    const float* __restrict__ m2, const float* __restrict__ v2,
    const float* __restrict__ W3, const float* __restrict__ b3,
    _Float16* __restrict__ wsh, float* __restrict__ wsf)
{
    int t = blockIdx.x * 256 + threadIdx.x;
    if (t < 512) {                               // W1c
        int row = t >> 3, i = t & 7;
        float s1 = g1[row] * rsqrtf(v1[row] + EPSBN);
        float val;
        if (i < 4)      val = W1[i * 64 + row] * s1;
        else if (i == 4) val = (b1[row] - m1[row]) * s1 + be1[row];
        else             val = 0.f;
        wsh[WS_W1C + t] = (_Float16)val;
    } else if (t < 4608) {                       // W2F frag-major
        int e = t - 512;
        int chp = e >> 6;                        // ch' (output channel)
        int rem = e & 63;
        int qq = rem >> 4, kc = (rem >> 2) & 3, j = rem & 3;
        int ch = kc * 16 + qq * 4 + j;           // input channel
        float s2 = g2[chp] * rsqrtf(v2[chp] + EPSBN);
        wsh[t] = (_Float16)(W2[ch * 64 + chp] * s2);
    } else if (t < 12800) {                      // W3F frag-major, pre-swizzled
        int e = t - 4608;
        int o = e >> 6;                          // output channel
        int rem = e & 63;
        int php = rem >> 3, j8 = rem & 7;        // physical granule, elem
        int gl = php ^ (o & 7);                  // logical granule
        int idx = gl * 8 + j8;                   // position in frag-major row
        int qq = idx >> 4, kc = (idx >> 2) & 3, j = idx & 3;
        int ch = kc * 16 + qq * 4 + j;
        wsh[t] = (_Float16)W3[ch * 128 + o];
    } else if (t < 12864) {                      // c2
        int i = t - 12800;
        float s2 = g2[i] * rsqrtf(v2[i] + EPSBN);
        wsf[i] = (b2[i] - m2[i]) * s2 + be2[i];
    } else if (t < FOLD_THREADS) {               // b3
        int i = t - 12864;
        wsf[64 + i] = b3[i];
    }
}

static __device__ __forceinline__ f16x4 relu4(f32x4 a) {
    f16x4 h;
    h[0] = (_Float16)fmaxf(a[0], 0.f);
    h[1] = (_Float16)fmaxf(a[1], 0.f);
    h[2] = (_Float16)fmaxf(a[2], 0.f);
    h[3] = (_Float16)fmaxf(a[3], 0.f);
    return h;
}

__global__ __launch_bounds__(256, 3) void vfe_mfma(
    const float* __restrict__ vf, const int* __restrict__ vnp,
    const _Float16* __restrict__ wsh, const float* __restrict__ wsf,
    float* __restrict__ out)
{
    // ONLY LDS: block-shared W3 tile (pre-swizzled in d_ws -> linear copy).
    __shared__ __align__(16) _Float16 sW3[ODIM * HDIM];   // 16384 B

    const int tid  = threadIdx.x;
    const int wave = tid >> 6;
    const int lane = tid & 63;
    const int q    = lane >> 4;
    const int m16  = lane & 15;
    (void)wave;

    const int wavebase = blockIdx.x * 256 + (tid >> 6) * 64;  // 64 pts = 2 voxels
    const int voxA = wavebase >> 5;

    // ---- stage W3 (linear copy, already swizzled) ----
    {
        const f16x8* src = (const f16x8*)&wsh[WS_W3T];
        f16x8* dst = (f16x8*)sW3;
#pragma unroll
        for (int i = 0; i < 4; ++i) dst[tid + 256 * i] = src[tid + 256 * i];
    }

    const int nA = vnp[voxA];
    const int nB = vnp[voxA + 1];

    // ---- weight fragments from global (L2-resident) ----
    // A1[mt]: lane holds W1c[16mt+m16][k=4q+j]; row = {w0..w3, c1,0,0,0}
    f16x4 a1[4];
#pragma unroll
    for (int mt = 0; mt < 4; ++mt)
        a1[mt] = (q < 2) ? *(const f16x4*)&wsh[WS_W1C + (16 * mt + m16) * 8 + q * 4]
                         : (f16x4)0;
    // A2 packed: a2p[mt][h] = frags (kc=2h, kc=2h+1) for row ch'=16mt+m16
    f16x8 a2p[4][2];
#pragma unroll
    for (int mt = 0; mt < 4; ++mt)
#pragma unroll
        for (int h = 0; h < 2; ++h)
            a2p[mt][h] = *(const f16x8*)&wsh[WS_W2T + (16 * mt + m16) * 64 + q * 16 + h * 8];
    f32x4 c2v[4];
#pragma unroll
    for (int mt = 0; mt < 4; ++mt)
        c2v[mt] = *(const f32x4*)(wsf + mt * 16 + q * 4);
    float b3r[8];
#pragma unroll
    for (int nt = 0; nt < 8; ++nt) b3r[nt] = wsf[64 + nt * 16 + m16];

    // ---- point inputs, B1 fragments ----
    float4 xv[4];
#pragma unroll
    for (int g = 0; g < 4; ++g)
        xv[g] = *(const float4*)(vf + ((size_t)wavebase + g * 16 + m16) * 4);

    f16x4 bf[4];
#pragma unroll
    for (int g = 0; g < 4; ++g) {
        f16x4 b = (f16x4)0;
        if (q == 0) {
            b[0] = (_Float16)xv[g].x; b[1] = (_Float16)xv[g].y;
            b[2] = (_Float16)xv[g].z; b[3] = (_Float16)xv[g].w;
        } else if (q == 1) {
            b[0] = (_Float16)1.0f;                // homogeneous slot carries c1
        }
        bf[g] = b;
    }

    __syncthreads();                              // W3 tile ready (only barrier)

    // ======== PHASE 1: layer 1, D1[ch'][pt]; tile kc IS the B2 k-chunk frag ====
    f16x4 d1[4][4];                               // [g][kc]
#pragma unroll
    for (int g = 0; g < 4; ++g)
#pragma unroll
        for (int mt = 0; mt < 4; ++mt) {
            f32x4 acc = {0.f, 0.f, 0.f, 0.f};
            acc = __builtin_amdgcn_mfma_f32_16x16x16f16(a1[mt], bf[g], acc, 0, 0, 0);
            d1[g][mt] = relu4(acc);
        }

    // ======== PHASE 2: layer 2, D2[ch'][pt]; tile kc IS the A3 k-chunk frag ====
    f16x4 d2[4][4];                               // [g][kc]
#pragma unroll
    for (int g = 0; g < 4; ++g)
#pragma unroll
        for (int mt = 0; mt < 4; ++mt) {
            f32x4 acc = c2v[mt];
            acc = __builtin_amdgcn_mfma_f32_16x16x16f16(LO4(a2p[mt][0]), d1[g][0], acc, 0, 0, 0);
            acc = __builtin_amdgcn_mfma_f32_16x16x16f16(HI4(a2p[mt][0]), d1[g][1], acc, 0, 0, 0);
            acc = __builtin_amdgcn_mfma_f32_16x16x16f16(LO4(a2p[mt][1]), d1[g][2], acc, 0, 0, 0);
            acc = __builtin_amdgcn_mfma_f32_16x16x16f16(HI4(a2p[mt][1]), d1[g][3], acc, 0, 0, 0);
            d2[g][mt] = relu4(acc);
        }

    // ======== PHASE 3: layer 3 (D3[pt][o]), masked voxel max ========
    f32x4 macc4[4];
#pragma unroll
    for (int g = 0; g < 4; ++g) {
        const int n = (g < 2) ? nA : nB;
        const int slotbase = (g & 1) * 16 + q * 4;
#pragma unroll
        for (int r = 0; r < 4; ++r)
            macc4[g][r] = (slotbase + r < n) ? 0.f : -INFINITY;
    }

    float vmA[8], vmB[8];
#pragma unroll
    for (int nt = 0; nt < 8; ++nt) { vmA[nt] = -INFINITY; vmB[nt] = -INFINITY; }

#pragma unroll
    for (int nt = 0; nt < 8; ++nt) {
        const int o = nt * 16 + m16;
        // logical granules 2q, 2q+1 -> physical via XOR swizzle
        f16x8 p0 = *(const f16x8*)&sW3[o * 64 + ((2 * q + 0) ^ (m16 & 7)) * 8];
        f16x8 p1 = *(const f16x8*)&sW3[o * 64 + ((2 * q + 1) ^ (m16 & 7)) * 8];
#pragma unroll
        for (int g = 0; g < 4; ++g) {
            f32x4 acc = macc4[g];
            acc = __builtin_amdgcn_mfma_f32_16x16x16f16(d2[g][0], LO4(p0), acc, 0, 0, 0);
            acc = __builtin_amdgcn_mfma_f32_16x16x16f16(d2[g][1], HI4(p0), acc, 0, 0, 0);
            acc = __builtin_amdgcn_mfma_f32_16x16x16f16(d2[g][2], LO4(p1), acc, 0, 0, 0);
            acc = __builtin_amdgcn_mfma_f32_16x16x16f16(d2[g][3], HI4(p1), acc, 0, 0, 0);
            float m0 = fmaxf(fmaxf(acc[0], acc[1]), fmaxf(acc[2], acc[3]));
            if (g < 2) vmA[nt] = fmaxf(vmA[nt], m0);
            else       vmB[nt] = fmaxf(vmB[nt], m0);
        }
    }

    // ======== epilogue: cross-quad max, bias, store (2 voxels) ========
#pragma unroll
    for (int nt = 0; nt < 8; ++nt) {
        float t0 = vmA[nt];
        t0 = fmaxf(t0, __shfl_xor(t0, 16));
        t0 = fmaxf(t0, __shfl_xor(t0, 32));
        float t1 = vmB[nt];
        t1 = fmaxf(t1, __shfl_xor(t1, 16));
        t1 = fmaxf(t1, __shfl_xor(t1, 32));
        if (q == 0) out[(size_t)(voxA + 0) * ODIM + nt * 16 + m16] = t0 + b3r[nt];
        if (q == 1) out[(size_t)(voxA + 1) * ODIM + nt * 16 + m16] = t1 + b3r[nt];
    }
}

extern "C" void kernel_launch(void* const* d_in, const int* in_sizes, int n_in,
                              void* d_out, int out_size, void* d_ws, size_t ws_size,
                              hipStream_t stream) {
    const float* vf  = (const float*)d_in[0];
    const int*   vnp = (const int*)d_in[1];
    const float* W1  = (const float*)d_in[2];
    const float* b1  = (const float*)d_in[3];
    const float* g1  = (const float*)d_in[4];
    const float* be1 = (const float*)d_in[5];
    const float* m1  = (const float*)d_in[6];
    const float* v1  = (const float*)d_in[7];
    const float* W2  = (const float*)d_in[8];
    const float* b2  = (const float*)d_in[9];
    const float* g2  = (const float*)d_in[10];
    const float* be2 = (const float*)d_in[11];
    const float* m2  = (const float*)d_in[12];
    const float* v2  = (const float*)d_in[13];
    const float* W3  = (const float*)d_in[14];
    const float* b3  = (const float*)d_in[15];
    float* out = (float*)d_out;

    _Float16* wsh = (_Float16*)d_ws;
    float*    wsf = (float*)((char*)d_ws + WS_F32_BYTE);

    vfe_fold<<<(FOLD_THREADS + 255) / 256, 256, 0, stream>>>(
        W1, b1, g1, be1, m1, v1, W2, b2, g2, be2, m2, v2, W3, b3, wsh, wsf);

    const int blocks = (NVOX * PPTS) / 256;   // 6250
    vfe_mfma<<<blocks, 256, 0, stream>>>(vf, vnp, wsh, wsf, out);
}